// Round 10
// baseline (379.979 us; speedup 1.0000x reference)
//
#include <hip/hip_runtime.h>
#include <hip/hip_fp16.h>

#define NB 2
#define NPTS 8192
#define NQ 4096
#define MTOT 8192      // NB*NQ
#define SP 16
#define SD 32
#define CIN 32
#define CP 32
#define CF 64
#define NROI 128       // NB*64
#define RADIUS_C 0.8f
#define MIN_R_C 0.01f
#define DIV_COEF_C 10.0f

// ---- spatial grid (cell = radius = 0.8; scene = [10,10,4]) ----------------
#define INV_CS 1.25f
#define NCX 13
#define NCY 13
#define NCZ 5
#define NCELL (NCX * NCY * NCZ)   // 845

// ---------------- device-global scratch (fully rewritten every call) -------
__device__ int    g_idx_p[MTOT * SP];
__device__ int    g_empty_p[MTOT];
__device__ int    g_idx_d[MTOT * SD];
__device__ int    g_empty_d[MTOT];
__device__ int    g_cellcnt[NB][NCELL];
__device__ int    g_cellcur[NB][NCELL];
__device__ int    g_cellstart[NB][NCELL + 1];
__device__ float4 g_cellxyzw[NB][NPTS];   // packed (x,y,z,index) per reordered point
// activation buffers: p-branch fp32 (16.7MB), f-branch fp16 (33.5MB)
__device__ unsigned char g_xa[(size_t)MTOT * SD * CF * 2];
__device__ unsigned char g_xb[(size_t)MTOT * SD * CF * 2];
__device__ unsigned int g_w1h[CF * CF / 2];       // W1 as half2 pairs: [ch][c2]
__device__ float  g_psT[CF * 2048];               // BN partials, transposed [ch][block]
__device__ float  g_pqT[CF * 2048];
__device__ float  g_bnscale[4][CF];               // 0=p0 1=p1 2=f0 3=f1
__device__ float  g_bnshift[4][CF];
__device__ float  g_rroi[NROI];

typedef _Float16 h2v __attribute__((ext_vector_type(2)));
__device__ __forceinline__ float fdot2f(unsigned int a, unsigned int b, float c) {
#if defined(__has_builtin)
#if __has_builtin(__builtin_amdgcn_fdot2)
    h2v ha, hb;
    ha = *(h2v*)&a; hb = *(h2v*)&b;
    return __builtin_amdgcn_fdot2(ha, hb, c, false);
#else
    __half2 ha = *(__half2*)&a, hb = *(__half2*)&b;
    float2 fa = __half22float2(ha), fb = __half22float2(hb);
    return fmaf(fa.x, fb.x, fmaf(fa.y, fb.y, c));
#endif
#else
    __half2 ha = *(__half2*)&a, hb = *(__half2*)&b;
    float2 fa = __half22float2(ha), fb = __half22float2(hb);
    return fmaf(fa.x, fb.x, fmaf(fa.y, fb.y, c));
#endif
}

__device__ __forceinline__ int cell_of(float x, float y, float z) {
    int cx = min(NCX - 1, max(0, (int)floorf(x * INV_CS)));
    int cy = min(NCY - 1, max(0, (int)floorf(y * INV_CS)));
    int cz = min(NCZ - 1, max(0, (int)floorf(z * INV_CS)));
    return (cz * NCY + cy) * NCX + cx;
}

// ====== setup: xyz copy + W1 pack + cellcnt zero ===========================
#define SETUP_N (MTOT * 3 + CF * CF / 2 + NB * NCELL)
__global__ void setup_kernel(const float* __restrict__ rois, const float* __restrict__ fw1,
                             float* __restrict__ out) {
    int i = blockIdx.x * 256 + threadIdx.x;
    if (i < MTOT * 3) { out[i] = rois[i]; return; }
    i -= MTOT * 3;
    if (i < CF * CF / 2) {
        int ch = i >> 5, c2 = i & 31;
        __half2 h = __floats2half2_rn(fw1[(2 * c2) * CF + ch], fw1[(2 * c2 + 1) * CF + ch]);
        g_w1h[i] = *(unsigned int*)&h;
        return;
    }
    i -= CF * CF / 2;
    if (i < NB * NCELL) ((int*)g_cellcnt)[i] = 0;
}

// ================= grid build (shared by both bq phases) ====================
__global__ void grid_count_kernel(const float* __restrict__ xyz) {
    int i = blockIdx.x * 256 + threadIdx.x;   // 0..16383
    int b = i >> 13;
    int cell = cell_of(xyz[(size_t)i * 3 + 0], xyz[(size_t)i * 3 + 1], xyz[(size_t)i * 3 + 2]);
    atomicAdd(&g_cellcnt[b][cell], 1);
}

__global__ void grid_prefix_kernel() {     // one block per batch
    __shared__ int sc[1024];
    int b = blockIdx.x, tid = threadIdx.x;
    int v = (tid < NCELL) ? g_cellcnt[b][tid] : 0;
    sc[tid] = v;
    __syncthreads();
    for (int off = 1; off < 1024; off <<= 1) {
        int add = (tid >= off) ? sc[tid - off] : 0;
        __syncthreads();
        sc[tid] += add;
        __syncthreads();
    }
    if (tid < NCELL) {
        int excl = sc[tid] - v;
        g_cellstart[b][tid] = excl;
        g_cellcur[b][tid] = excl;
    }
    if (tid == 0) g_cellstart[b][NCELL] = NPTS;
}

__global__ void grid_scatter_kernel(const float* __restrict__ xyz) {
    int i = blockIdx.x * 256 + threadIdx.x;
    int b = i >> 13, il = i & (NPTS - 1);
    float x = xyz[(size_t)i * 3 + 0];
    float y = xyz[(size_t)i * 3 + 1];
    float z = xyz[(size_t)i * 3 + 2];
    int cell = cell_of(x, y, z);
    int pos = atomicAdd(&g_cellcur[b][cell], 1);
    g_cellxyzw[b][pos] = make_float4(x, y, z, __int_as_float(il));
}

// ======= ball query: wave/query; LDS candidate append + rank-by-count ======
template <int NS>
__launch_bounds__(256, 8)
__global__ void bq_grid_kernel(const float* __restrict__ xyz, const float* __restrict__ newxyz) {
    __shared__ int s_cand[4][512];
    __shared__ int s_meta[4][2];   // [0]=count, [1]=min element
    int tid = threadIdx.x, wv = tid >> 6, lane = tid & 63;
    int q = blockIdx.x * 4 + wv;
    int b = q >> 12;
    float qx = newxyz[q * 3 + 0], qy = newxyz[q * 3 + 1], qz = newxyz[q * 3 + 2];
    float r = (NS == SP) ? RADIUS_C : g_rroi[q >> 6];
    float r2 = r * r;
    int* idx_out   = (NS == SP) ? g_idx_p   : g_idx_d;
    int* empty_out = (NS == SP) ? g_empty_p : g_empty_d;

    if (lane == 0) s_meta[wv][0] = 0;
    __asm__ volatile("s_waitcnt lgkmcnt(0)" ::: "memory");

    float rp = r + 1e-4f;
    int xlo = max(0, min(NCX - 1, (int)floorf((qx - rp) * INV_CS)));
    int xhi = max(0, min(NCX - 1, (int)floorf((qx + rp) * INV_CS)));
    int ylo = max(0, min(NCY - 1, (int)floorf((qy - rp) * INV_CS)));
    int yhi = max(0, min(NCY - 1, (int)floorf((qy + rp) * INV_CS)));
    int zlo = max(0, min(NCZ - 1, (int)floorf((qz - rp) * INV_CS)));
    int zhi = max(0, min(NCZ - 1, (int)floorf((qz + rp) * INV_CS)));
    int nx = xhi - xlo + 1, ny = yhi - ylo + 1, nz = zhi - zlo + 1;
    int ncell = nx * ny * nz;

    bool ovf = false;
    for (int ci = lane; ci < ncell; ci += 64) {
        int cx = xlo + (ci % nx);
        int t1 = ci / nx;
        int cy = ylo + (t1 % ny);
        int cz = zlo + (t1 / ny);
        int cell = (cz * NCY + cy) * NCX + cx;
        int s0 = g_cellstart[b][cell], e0 = g_cellstart[b][cell + 1];
        for (int e = s0; e < e0; ++e) {
            float4 v = g_cellxyzw[b][e];
            float dx = qx - v.x, dy = qy - v.y, dz = qz - v.z;
            if (dx * dx + dy * dy + dz * dz < r2) {
                int pos = atomicAdd(&s_meta[wv][0], 1);
                if (pos < 512) s_cand[wv][pos] = __float_as_int(v.w);
                else ovf = true;
            }
        }
    }
    __asm__ volatile("s_waitcnt lgkmcnt(0) vmcnt(0)" ::: "memory");
    int cnt = s_meta[wv][0];

    if (__ballot(ovf)) {   // rare: >512 in-ball — original ordered full scan
        const float* xb = xyz + (size_t)b * NPTS * 3;
        int cnt2 = 0, first_idx = 0;
        for (int g = 0; g < NPTS / 64 && cnt2 < NS; ++g) {
            int p = (g << 6) + lane;
            float dx = qx - xb[3 * p + 0];
            float dy = qy - xb[3 * p + 1];
            float dz = qz - xb[3 * p + 2];
            bool valid = (dx * dx + dy * dy + dz * dz) < r2;
            unsigned long long mask = __ballot(valid);
            if (cnt2 == 0 && mask) first_idx = (g << 6) + (int)__builtin_ctzll(mask);
            int pos = cnt2 + __popcll(mask & ((1ull << lane) - 1ull));
            if (valid && pos < NS) idx_out[q * NS + pos] = p;
            cnt2 += (int)__popcll(mask);
        }
        if (cnt2 == 0) {
            if (lane < NS) idx_out[q * NS + lane] = 0;
            if (lane == 0) empty_out[q] = 1;
        } else {
            int filled = cnt2 < NS ? cnt2 : NS;
            if (lane >= filled && lane < NS) idx_out[q * NS + lane] = first_idx;
            if (lane == 0) empty_out[q] = 0;
        }
        return;
    }

    if (cnt == 0) {
        if (lane < NS) idx_out[q * NS + lane] = 0;
        if (lane == 0) empty_out[q] = 1;
        return;
    }
    // rank-by-count: j-loop reads are wave-uniform -> LDS broadcast (free)
    for (int i = lane; i < cnt; i += 64) {
        int c = s_cand[wv][i];
        int rank = 0;
        for (int j = 0; j < cnt; ++j) rank += (s_cand[wv][j] < c) ? 1 : 0;
        if (rank < NS) idx_out[q * NS + rank] = c;
        if (rank == 0) s_meta[wv][1] = c;
    }
    __asm__ volatile("s_waitcnt lgkmcnt(0)" ::: "memory");
    if (cnt < NS && lane >= cnt && lane < NS) idx_out[q * NS + lane] = s_meta[wv][1];
    if (lane == 0) empty_out[q] = 0;
}

// ============ 3-pass MLP =====================================================
// PASS A (split-channel): 256 threads = 128 rows x 2 channel-halves.
// Per-thread chain halved (acc[CH/2]); LDS <= 19 KB; 6 blocks/CU.
template <int NS, int CH, bool HALF>
__launch_bounds__(256, 6)
__global__ void mlp_passA_kernel(const float* __restrict__ xyz, const float* __restrict__ feats,
                                 const float* __restrict__ newxyz, const float* __restrict__ W0,
                                 void* __restrict__ xout_) {
    constexpr int GSTR = 37;        // gather row stride (35 used)
    constexpr int SST  = CH + 2;    // stats/store transpose stride
    constexpr int CHH  = CH / 2;    // channels per thread
    __shared__ float buf[128 * GSTR];   // 18.9 KB; reused for transpose
    __shared__ float ls[256], lq[256];
    int tid = threadIdx.x;
    int row = tid & 127, half = tid >> 7;   // half is wave-uniform
    int rowbase = blockIdx.x * 128;
    int grow = rowbase + row;
    int q = grow / NS, b = q >> 12;
    const int* idx_arr = (NS == SP) ? g_idx_p : g_idx_d;
    const int* emp_arr = (NS == SP) ? g_empty_p : g_empty_d;
    {
        float* dst = &buf[row * GSTR];
        if (emp_arr[q]) {
            int c0 = half ? 18 : 0, c1 = half ? 35 : 18;
            for (int c = c0; c < c1; ++c) dst[c] = 0.f;
        } else {
            int idx = idx_arr[grow];
            if (half == 0) {
                const float* xp = xyz + (size_t)b * NPTS * 3 + idx * 3;
                dst[0] = xp[0] - newxyz[q * 3 + 0];
                dst[1] = xp[1] - newxyz[q * 3 + 1];
                dst[2] = xp[2] - newxyz[q * 3 + 2];
            }
            const float4* fp = (const float4*)(feats + (size_t)b * NPTS * CIN + (size_t)idx * CIN);
#pragma unroll
            for (int j = 0; j < 4; ++j) {
                float4 v = fp[half * 4 + j];
                float* d = dst + 3 + (half * 4 + j) * 4;
                d[0] = v.x; d[1] = v.y; d[2] = v.z; d[3] = v.w;
            }
        }
    }
    __syncthreads();    // row written by 2 threads
    float acc[CHH];
#pragma unroll
    for (int ch = 0; ch < CHH; ++ch) acc[ch] = 0.f;
    {
        const float* inrow = &buf[row * GSTR];
        const float* w = W0 + half * CHH;
        for (int c = 0; c < 35; ++c) {
            float h = inrow[c];
#pragma unroll
            for (int ch = 0; ch < CHH; ++ch) acc[ch] = fmaf(h, w[c * CH + ch], acc[ch]);
        }
    }
    // stats + coalesced store via 2-pass LDS transpose (64 rows/pass)
    float* xf = (float*)xout_;
    __half* xh = (__half*)xout_;
    float sum = 0.f, sq = 0.f;
#pragma unroll
    for (int p = 0; p < 2; ++p) {
        __syncthreads();
        if ((row >> 6) == p) {
            float* srow = &buf[(row & 63) * SST + half * CHH];
#pragma unroll
            for (int ch = 0; ch < CHH; ++ch) srow[ch] = acc[ch];
        }
        __syncthreads();
        if (CH == 64) {
            int ch = tid & 63, rg = tid >> 6;
            for (int r = 0; r < 16; ++r) {
                float v = buf[(rg * 16 + r) * SST + ch];
                size_t o = (size_t)(rowbase + p * 64 + rg * 16 + r) * CH + ch;
                if (HALF) xh[o] = __float2half_rn(v); else xf[o] = v;
                sum += v; sq += v * v;
            }
        } else {
            int ch = tid & 31, rg = tid >> 5;
            for (int r = 0; r < 8; ++r) {
                float v = buf[(rg * 8 + r) * SST + ch];
                size_t o = (size_t)(rowbase + p * 64 + rg * 8 + r) * CH + ch;
                if (HALF) xh[o] = __float2half_rn(v); else xf[o] = v;
                sum += v; sq += v * v;
            }
        }
    }
    ls[tid] = sum; lq[tid] = sq;
    __syncthreads();
    if (CH == 64) {
        if (tid < 64) {
            g_psT[tid * 2048 + blockIdx.x] = ls[tid] + ls[64 + tid] + ls[128 + tid] + ls[192 + tid];
            g_pqT[tid * 2048 + blockIdx.x] = lq[tid] + lq[64 + tid] + lq[128 + tid] + lq[192 + tid];
        }
    } else {
        if (tid < 32) {
            float s = 0.f, qq = 0.f;
#pragma unroll
            for (int k = 0; k < 8; ++k) { s += ls[tid + 32 * k]; qq += lq[tid + 32 * k]; }
            g_psT[tid * 2048 + blockIdx.x] = s;
            g_pqT[tid * 2048 + blockIdx.x] = qq;
        }
    }
}

// PASS B (p-branch, fp32): stream x0p -> BN0+ReLU -> L1 -> store x1p + stats
template <int NS, int CH>
__launch_bounds__(128, 4)
__global__ void mlp_passB_kernel(const float* __restrict__ W1, const float* __restrict__ xin,
                                 float* __restrict__ xout, int bn0) {
    constexpr int HSTR = 33;
    constexpr int SST  = CH + 2;
    __shared__ float buf[128 * 37];
    __shared__ float ls[128], lq[128];
    int tid = threadIdx.x;
    int rowbase = blockIdx.x * 128;
    const float* sc0 = g_bnscale[bn0];
    const float* sh0 = g_bnshift[bn0];
    float acc2[CH];
#pragma unroll
    for (int ch = 0; ch < CH; ++ch) acc2[ch] = 0.f;
    const float4* src = (const float4*)xin;
#pragma unroll
    for (int hc = 0; hc < CH / 32; ++hc) {
        if (hc) __syncthreads();
#pragma unroll
        for (int k = 0; k < 8; ++k) {
            int o4 = tid + k * 128;       // 0..1023
            int rloc = o4 >> 3, j = o4 & 7;
            int c = 4 * j, gc = hc * 32 + c;
            float4 v = src[(size_t)(rowbase + rloc) * (CH / 4) + hc * 8 + j];
            float* d = &buf[rloc * HSTR + c];
            d[0] = fmaxf(fmaf(v.x, sc0[gc + 0], sh0[gc + 0]), 0.f);
            d[1] = fmaxf(fmaf(v.y, sc0[gc + 1], sh0[gc + 1]), 0.f);
            d[2] = fmaxf(fmaf(v.z, sc0[gc + 2], sh0[gc + 2]), 0.f);
            d[3] = fmaxf(fmaf(v.w, sc0[gc + 3], sh0[gc + 3]), 0.f);
        }
        __syncthreads();
        const float* hrow = &buf[tid * HSTR];
        for (int c = 0; c < 32; ++c) {
            float h = hrow[c];
#pragma unroll
            for (int ch = 0; ch < CH; ++ch)
                acc2[ch] = fmaf(h, W1[(hc * 32 + c) * CH + ch], acc2[ch]);
        }
    }
    float sum = 0.f, sq = 0.f;
#pragma unroll
    for (int p = 0; p < 2; ++p) {
        __syncthreads();
        if ((tid >> 6) == p) {
            float* srow = &buf[(tid & 63) * SST];
#pragma unroll
            for (int ch = 0; ch < CH; ++ch) srow[ch] = acc2[ch];
        }
        __syncthreads();
        int ch = tid & 31, rg = tid >> 5;
        for (int r = 0; r < 16; ++r) {
            float v = buf[(rg * 16 + r) * SST + ch];
            xout[(size_t)(rowbase + p * 64 + rg * 16 + r) * CH + ch] = v;
            sum += v; sq += v * v;
        }
    }
    ls[tid] = sum; lq[tid] = sq;
    __syncthreads();
    if (tid < 32) {
        g_psT[tid * 2048 + blockIdx.x] = ls[tid] + ls[32 + tid] + ls[64 + tid] + ls[96 + tid];
        g_pqT[tid * 2048 + blockIdx.x] = lq[tid] + lq[32 + tid] + lq[64 + tid] + lq[96 + tid];
    }
}

// PASS B (f-branch, fp16, split-channel): 256 threads = 128 rows x 2 halves;
// packed half2 LDS + dot2; coalesced transpose store + stats.
__launch_bounds__(256, 6)
__global__ void mlp_fB_kernel(const __half* __restrict__ xin, __half* __restrict__ xout) {
    __shared__ unsigned int hp[128 * 33];   // 16.9 KB; aliased as float [64][66]
    __shared__ float ls[256], lq[256];
    int tid = threadIdx.x;
    int row = tid & 127, half = tid >> 7;   // half is wave-uniform
    int rowbase = blockIdx.x * 128;
    const float* sc0 = g_bnscale[2];
    const float* sh0 = g_bnshift[2];
    {
        const float4* src = (const float4*)xin;
#pragma unroll
        for (int k = 0; k < 4; ++k) {
            int o4 = tid + k * 256;       // 0..1023
            int rloc = o4 >> 3, j = o4 & 7;
            float4 v = src[(size_t)(rowbase + rloc) * 8 + j];
            const __half2* ph = (const __half2*)&v;   // 4 half2 pairs
            unsigned int* d = &hp[rloc * 33 + 4 * j];
#pragma unroll
            for (int m = 0; m < 4; ++m) {
                float2 f = __half22float2(ph[m]);
                int gc = 8 * j + 2 * m;
                float a = fmaxf(fmaf(f.x, sc0[gc + 0], sh0[gc + 0]), 0.f);
                float bb = fmaxf(fmaf(f.y, sc0[gc + 1], sh0[gc + 1]), 0.f);
                __half2 hh = __floats2half2_rn(a, bb);
                d[m] = *(unsigned int*)&hh;
            }
        }
    }
    __syncthreads();
    float acc[32];
#pragma unroll
    for (int ch = 0; ch < 32; ++ch) acc[ch] = 0.f;
    {
        const unsigned int* hrow = &hp[row * 33];
        const unsigned int* wbase = g_w1h + (half * 32) * 32;
#pragma unroll
        for (int c2 = 0; c2 < 32; ++c2) {
            unsigned int h2 = hrow[c2];
#pragma unroll
            for (int ch = 0; ch < 32; ++ch)
                acc[ch] = fdot2f(h2, wbase[ch * 32 + c2], acc[ch]);
        }
    }
    // transpose: coalesced half store + stats from same LDS pass
    float* fview = (float*)hp;              // [64][66] = 4224 floats, exact fit
    float sum = 0.f, sq = 0.f;
#pragma unroll
    for (int p = 0; p < 2; ++p) {
        __syncthreads();
        if ((row >> 6) == p) {
            float* srow = &fview[(row & 63) * 66 + half * 32];
#pragma unroll
            for (int ch = 0; ch < 32; ++ch) srow[ch] = acc[ch];
        }
        __syncthreads();
        int ch = tid & 63, rg = tid >> 6;
        for (int r = 0; r < 16; ++r) {
            float v = fview[(rg * 16 + r) * 66 + ch];
            xout[(size_t)(rowbase + p * 64 + rg * 16 + r) * CF + ch] = __float2half_rn(v);
            sum += v; sq += v * v;
        }
    }
    ls[tid] = sum; lq[tid] = sq;
    __syncthreads();
    if (tid < 64) {
        g_psT[tid * 2048 + blockIdx.x] = ls[tid] + ls[64 + tid] + ls[128 + tid] + ls[192 + tid];
        g_pqT[tid * 2048 + blockIdx.x] = lq[tid] + lq[64 + tid] + lq[128 + tid] + lq[192 + tid];
    }
}

// -------- BN stats finalize: one block per channel, coalesced, tree-reduce --
__global__ void finalize_kernel(const float* __restrict__ gamma, const float* __restrict__ beta,
                                float n, int layer, int nblocks) {
    __shared__ double l_s[256], l_q[256];
    int ch = blockIdx.x, tid = threadIdx.x;
    double s = 0, q = 0;
    for (int i = tid; i < nblocks; i += 256) { s += g_psT[ch * 2048 + i]; q += g_pqT[ch * 2048 + i]; }
    l_s[tid] = s; l_q[tid] = q; __syncthreads();
    for (int off = 128; off > 0; off >>= 1) {
        if (tid < off) { l_s[tid] += l_s[tid + off]; l_q[tid] += l_q[tid + off]; }
        __syncthreads();
    }
    if (tid == 0) {
        double mu = l_s[0] / (double)n;
        double var = l_q[0] / (double)n - mu * mu;
        if (var < 0) var = 0;
        double sc = (double)gamma[ch] / sqrt(var + 1e-5);
        g_bnscale[layer][ch] = (float)sc;
        g_bnshift[layer][ch] = (float)((double)beta[ch] - mu * sc);
    }
}

// PASS C deform: stream x1f (fp16), BN1+ReLU, sigmoid weight, max over 32 -> out
__global__ void passC_f_kernel(const float* __restrict__ xyz, const float* __restrict__ newxyz,
                               const float* __restrict__ td, const __half* __restrict__ xin,
                               float* __restrict__ out) {
    __shared__ float lw[64];
    int tid = threadIdx.x;
    int qpair = blockIdx.x * 2;
    if (tid < 64) {
        int ql = tid >> 5, s = tid & 31;
        int q = qpair + ql;
        float wv = 0.f;
        if (!g_empty_d[q]) {
            int idx = g_idx_d[q * SD + s];
            int b = q >> 12;
            float dx = xyz[(size_t)b * NPTS * 3 + idx * 3 + 0] - newxyz[q * 3 + 0];
            float dy = xyz[(size_t)b * NPTS * 3 + idx * 3 + 1] - newxyz[q * 3 + 1];
            float dz = xyz[(size_t)b * NPTS * 3 + idx * 3 + 2] - newxyz[q * 3 + 2];
            float dist = sqrtf(dx * dx + dy * dy + dz * dz);
            float rq = g_rroi[q >> 6];
            wv = 1.f / (1.f + expf(-(rq - dist) / td[0]));
        }
        lw[tid] = wv;
    }
    __syncthreads();
    int ql = tid >> 6, ch = tid & 63;
    int q = qpair + ql;
    float sc = g_bnscale[3][ch], sh = g_bnshift[3][ch];
    float m = 0.f;
    for (int s = 0; s < SD; ++s) {
        float v = __half2float(xin[((size_t)q * SD + s) * CF + ch]);
        m = fmaxf(m, lw[ql * 32 + s] * fmaxf(fmaf(v, sc, sh), 0.f));
    }
    out[MTOT * 3 + (size_t)q * CF + ch] = m;
}

// PASS C pred fused with per-roi fc reduce: one block per roi
__global__ void passC_roi_kernel(const float* __restrict__ fcw, const float* __restrict__ fcb,
                                 const float* __restrict__ roif, const float* __restrict__ xin) {
    __shared__ float red[256];
    int tid = threadIdx.x;
    int roi = blockIdx.x;
    int ch = tid & 31, qs = tid >> 5;
    float sc = g_bnscale[1][ch], sh = g_bnshift[1][ch];
    float acc = 0.f;
    for (int ql = qs; ql < 64; ql += 8) {
        int q = roi * 64 + ql;
        float m = 0.f;
        for (int s = 0; s < SP; ++s) {
            float v = xin[(size_t)(q * SP + s) * CP + ch] * sc + sh;
            m = fmaxf(m, fmaxf(v, 0.f));
        }
        acc += m * fcw[ql * CP + ch];
    }
    if (tid < 128) acc += roif[roi * 128 + tid] * fcw[2048 + tid];
    red[tid] = acc;
    __syncthreads();
    for (int off = 128; off > 0; off >>= 1) {
        if (tid < off) red[tid] += red[tid + off];
        __syncthreads();
    }
    if (tid == 0)
        g_rroi[roi] = fmaxf((red[0] + fcb[0]) / DIV_COEF_C + RADIUS_C, MIN_R_C);
}

extern "C" void kernel_launch(void* const* d_in, const int* in_sizes, int n_in,
                              void* d_out, int out_size, void* d_ws, size_t ws_size,
                              hipStream_t stream) {
    const float* xyz   = (const float*)d_in[0];
    const float* feats = (const float*)d_in[1];
    const float* rois  = (const float*)d_in[2];
    const float* roif  = (const float*)d_in[3];
    const float* td    = (const float*)d_in[4];
    const float* pw0 = (const float*)d_in[5];
    const float* pg0 = (const float*)d_in[6];
    const float* pb0 = (const float*)d_in[7];
    const float* pw1 = (const float*)d_in[8];
    const float* pg1 = (const float*)d_in[9];
    const float* pb1 = (const float*)d_in[10];
    const float* fw0 = (const float*)d_in[11];
    const float* fg0 = (const float*)d_in[12];
    const float* fb0 = (const float*)d_in[13];
    const float* fw1 = (const float*)d_in[14];
    const float* fg1 = (const float*)d_in[15];
    const float* fb1 = (const float*)d_in[16];
    const float* fcw = (const float*)d_in[17];
    const float* fcb = (const float*)d_in[18];
    float* out = (float*)d_out;

    void* xa; hipGetSymbolAddress(&xa, HIP_SYMBOL(g_xa));
    void* xb; hipGetSymbolAddress(&xb, HIP_SYMBOL(g_xb));

    setup_kernel<<<(SETUP_N + 255) / 256, 256, 0, stream>>>(rois, fw1, out);
    grid_count_kernel<<<64, 256, 0, stream>>>(xyz);
    grid_prefix_kernel<<<2, 1024, 0, stream>>>();
    grid_scatter_kernel<<<64, 256, 0, stream>>>(xyz);

    // pred branch (16 samples, 32 ch, all fp32)
    bq_grid_kernel<SP><<<MTOT / 4, 256, 0, stream>>>(xyz, rois);
    mlp_passA_kernel<SP, CP, false><<<1024, 256, 0, stream>>>(xyz, feats, rois, pw0, xa);
    finalize_kernel<<<CP, 256, 0, stream>>>(pg0, pb0, (float)(MTOT * SP), 0, 1024);
    mlp_passB_kernel<SP, CP><<<1024, 128, 0, stream>>>(pw1, (const float*)xa, (float*)xb, 0);
    finalize_kernel<<<CP, 256, 0, stream>>>(pg1, pb1, (float)(MTOT * SP), 1, 1024);
    passC_roi_kernel<<<NROI, 256, 0, stream>>>(fcw, fcb, roif, (const float*)xb);

    // deform branch (32 samples, 64 ch, fp16 intermediates)
    bq_grid_kernel<SD><<<MTOT / 4, 256, 0, stream>>>(xyz, rois);
    mlp_passA_kernel<SD, CF, true><<<2048, 256, 0, stream>>>(xyz, feats, rois, fw0, xa);
    finalize_kernel<<<CF, 256, 0, stream>>>(fg0, fb0, (float)(MTOT * SD), 2, 2048);
    mlp_fB_kernel<<<2048, 256, 0, stream>>>((const __half*)xa, (__half*)xb);
    finalize_kernel<<<CF, 256, 0, stream>>>(fg1, fb1, (float)(MTOT * SD), 3, 2048);
    passC_f_kernel<<<MTOT / 2, 128, 0, stream>>>(xyz, rois, td, (const __half*)xb, out);
}

// Round 11
// 272.761 us; speedup vs baseline: 1.3931x; 1.3931x over previous
//
#include <hip/hip_runtime.h>
#include <hip/hip_fp16.h>

#define NB 2
#define NPTS 8192
#define NQ 4096
#define MTOT 8192      // NB*NQ
#define SP 16
#define SD 32
#define CIN 32
#define CP 32
#define CF 64
#define NROI 128       // NB*64
#define RADIUS_C 0.8f
#define MIN_R_C 0.01f
#define DIV_COEF_C 10.0f

// ---- spatial grid (cell = radius = 0.8; scene = [10,10,4]) ----------------
#define INV_CS 1.25f
#define NCX 13
#define NCY 13
#define NCZ 5
#define NCELL (NCX * NCY * NCZ)   // 845

// ---------------- device-global scratch (fully rewritten every call) -------
__device__ int    g_idx_p[MTOT * SP];
__device__ int    g_empty_p[MTOT];
__device__ int    g_idx_d[MTOT * SD];
__device__ int    g_empty_d[MTOT];
__device__ int    g_cellcnt[NB][NCELL];
__device__ int    g_cellcur[NB][NCELL];
__device__ int    g_cellstart[NB][NCELL + 1];
__device__ float4 g_cellxyzw[NB][NPTS];   // packed (x,y,z,index) per reordered point
// activation buffers: p-branch fp32 (16.7MB), f-branch fp16 (33.5MB)
__device__ unsigned char g_xa[(size_t)MTOT * SD * CF * 2];
__device__ unsigned char g_xb[(size_t)MTOT * SD * CF * 2];
__device__ unsigned int g_w1h[CF * CF / 2];       // W1 as half2 pairs: [ch][c2]
__device__ float  g_psT[CF * 2048];               // BN partials, transposed [ch][block]
__device__ float  g_pqT[CF * 2048];
__device__ float  g_bnscale[4][CF];               // 0=p0 1=p1 2=f0 3=f1
__device__ float  g_bnshift[4][CF];
__device__ float  g_rroi[NROI];

typedef _Float16 h2v __attribute__((ext_vector_type(2)));
__device__ __forceinline__ float fdot2f(unsigned int a, unsigned int b, float c) {
#if defined(__has_builtin)
#if __has_builtin(__builtin_amdgcn_fdot2)
    h2v ha, hb;
    ha = *(h2v*)&a; hb = *(h2v*)&b;
    return __builtin_amdgcn_fdot2(ha, hb, c, false);
#else
    __half2 ha = *(__half2*)&a, hb = *(__half2*)&b;
    float2 fa = __half22float2(ha), fb = __half22float2(hb);
    return fmaf(fa.x, fb.x, fmaf(fa.y, fb.y, c));
#endif
#else
    __half2 ha = *(__half2*)&a, hb = *(__half2*)&b;
    float2 fa = __half22float2(ha), fb = __half22float2(hb);
    return fmaf(fa.x, fb.x, fmaf(fa.y, fb.y, c));
#endif
}

__device__ __forceinline__ int cell_of(float x, float y, float z) {
    int cx = min(NCX - 1, max(0, (int)floorf(x * INV_CS)));
    int cy = min(NCY - 1, max(0, (int)floorf(y * INV_CS)));
    int cz = min(NCZ - 1, max(0, (int)floorf(z * INV_CS)));
    return (cz * NCY + cy) * NCX + cx;
}

// ====== setup: xyz copy + W1 pack + cellcnt zero ===========================
#define SETUP_N (MTOT * 3 + CF * CF / 2 + NB * NCELL)
__global__ void setup_kernel(const float* __restrict__ rois, const float* __restrict__ fw1,
                             float* __restrict__ out) {
    int i = blockIdx.x * 256 + threadIdx.x;
    if (i < MTOT * 3) { out[i] = rois[i]; return; }
    i -= MTOT * 3;
    if (i < CF * CF / 2) {
        int ch = i >> 5, c2 = i & 31;
        __half2 h = __floats2half2_rn(fw1[(2 * c2) * CF + ch], fw1[(2 * c2 + 1) * CF + ch]);
        g_w1h[i] = *(unsigned int*)&h;
        return;
    }
    i -= CF * CF / 2;
    if (i < NB * NCELL) ((int*)g_cellcnt)[i] = 0;
}

// ================= grid build (shared by both bq phases) ====================
__global__ void grid_count_kernel(const float* __restrict__ xyz) {
    int i = blockIdx.x * 256 + threadIdx.x;   // 0..16383
    int b = i >> 13;
    int cell = cell_of(xyz[(size_t)i * 3 + 0], xyz[(size_t)i * 3 + 1], xyz[(size_t)i * 3 + 2]);
    atomicAdd(&g_cellcnt[b][cell], 1);
}

__global__ void grid_prefix_kernel() {     // one block per batch
    __shared__ int sc[1024];
    int b = blockIdx.x, tid = threadIdx.x;
    int v = (tid < NCELL) ? g_cellcnt[b][tid] : 0;
    sc[tid] = v;
    __syncthreads();
    for (int off = 1; off < 1024; off <<= 1) {
        int add = (tid >= off) ? sc[tid - off] : 0;
        __syncthreads();
        sc[tid] += add;
        __syncthreads();
    }
    if (tid < NCELL) {
        int excl = sc[tid] - v;
        g_cellstart[b][tid] = excl;
        g_cellcur[b][tid] = excl;
    }
    if (tid == 0) g_cellstart[b][NCELL] = NPTS;
}

__global__ void grid_scatter_kernel(const float* __restrict__ xyz) {
    int i = blockIdx.x * 256 + threadIdx.x;
    int b = i >> 13, il = i & (NPTS - 1);
    float x = xyz[(size_t)i * 3 + 0];
    float y = xyz[(size_t)i * 3 + 1];
    float z = xyz[(size_t)i * 3 + 2];
    int cell = cell_of(x, y, z);
    int pos = atomicAdd(&g_cellcur[b][cell], 1);
    g_cellxyzw[b][pos] = make_float4(x, y, z, __int_as_float(il));
}

// ======= ball query: wave/query; LDS candidate append + rank-by-count ======
template <int NS>
__launch_bounds__(256, 8)
__global__ void bq_grid_kernel(const float* __restrict__ xyz, const float* __restrict__ newxyz) {
    __shared__ int s_cand[4][512];
    __shared__ int s_meta[4][2];   // [0]=count, [1]=min element
    int tid = threadIdx.x, wv = tid >> 6, lane = tid & 63;
    int q = blockIdx.x * 4 + wv;
    int b = q >> 12;
    float qx = newxyz[q * 3 + 0], qy = newxyz[q * 3 + 1], qz = newxyz[q * 3 + 2];
    float r = (NS == SP) ? RADIUS_C : g_rroi[q >> 6];
    float r2 = r * r;
    int* idx_out   = (NS == SP) ? g_idx_p   : g_idx_d;
    int* empty_out = (NS == SP) ? g_empty_p : g_empty_d;

    if (lane == 0) s_meta[wv][0] = 0;
    __asm__ volatile("s_waitcnt lgkmcnt(0)" ::: "memory");

    float rp = r + 1e-4f;
    int xlo = max(0, min(NCX - 1, (int)floorf((qx - rp) * INV_CS)));
    int xhi = max(0, min(NCX - 1, (int)floorf((qx + rp) * INV_CS)));
    int ylo = max(0, min(NCY - 1, (int)floorf((qy - rp) * INV_CS)));
    int yhi = max(0, min(NCY - 1, (int)floorf((qy + rp) * INV_CS)));
    int zlo = max(0, min(NCZ - 1, (int)floorf((qz - rp) * INV_CS)));
    int zhi = max(0, min(NCZ - 1, (int)floorf((qz + rp) * INV_CS)));
    int nx = xhi - xlo + 1, ny = yhi - ylo + 1, nz = zhi - zlo + 1;
    int ncell = nx * ny * nz;

    bool ovf = false;
    for (int ci = lane; ci < ncell; ci += 64) {
        int cx = xlo + (ci % nx);
        int t1 = ci / nx;
        int cy = ylo + (t1 % ny);
        int cz = zlo + (t1 / ny);
        int cell = (cz * NCY + cy) * NCX + cx;
        int s0 = g_cellstart[b][cell], e0 = g_cellstart[b][cell + 1];
        for (int e = s0; e < e0; ++e) {
            float4 v = g_cellxyzw[b][e];
            float dx = qx - v.x, dy = qy - v.y, dz = qz - v.z;
            if (dx * dx + dy * dy + dz * dz < r2) {
                int pos = atomicAdd(&s_meta[wv][0], 1);
                if (pos < 512) s_cand[wv][pos] = __float_as_int(v.w);
                else ovf = true;
            }
        }
    }
    __asm__ volatile("s_waitcnt lgkmcnt(0) vmcnt(0)" ::: "memory");
    int cnt = s_meta[wv][0];

    if (__ballot(ovf)) {   // rare: >512 in-ball — original ordered full scan
        const float* xb = xyz + (size_t)b * NPTS * 3;
        int cnt2 = 0, first_idx = 0;
        for (int g = 0; g < NPTS / 64 && cnt2 < NS; ++g) {
            int p = (g << 6) + lane;
            float dx = qx - xb[3 * p + 0];
            float dy = qy - xb[3 * p + 1];
            float dz = qz - xb[3 * p + 2];
            bool valid = (dx * dx + dy * dy + dz * dz) < r2;
            unsigned long long mask = __ballot(valid);
            if (cnt2 == 0 && mask) first_idx = (g << 6) + (int)__builtin_ctzll(mask);
            int pos = cnt2 + __popcll(mask & ((1ull << lane) - 1ull));
            if (valid && pos < NS) idx_out[q * NS + pos] = p;
            cnt2 += (int)__popcll(mask);
        }
        if (cnt2 == 0) {
            if (lane < NS) idx_out[q * NS + lane] = 0;
            if (lane == 0) empty_out[q] = 1;
        } else {
            int filled = cnt2 < NS ? cnt2 : NS;
            if (lane >= filled && lane < NS) idx_out[q * NS + lane] = first_idx;
            if (lane == 0) empty_out[q] = 0;
        }
        return;
    }

    if (cnt == 0) {
        if (lane < NS) idx_out[q * NS + lane] = 0;
        if (lane == 0) empty_out[q] = 1;
        return;
    }
    // rank-by-count: j-loop reads are wave-uniform -> LDS broadcast (free)
    for (int i = lane; i < cnt; i += 64) {
        int c = s_cand[wv][i];
        int rank = 0;
        for (int j = 0; j < cnt; ++j) rank += (s_cand[wv][j] < c) ? 1 : 0;
        if (rank < NS) idx_out[q * NS + rank] = c;
        if (rank == 0) s_meta[wv][1] = c;
    }
    __asm__ volatile("s_waitcnt lgkmcnt(0)" ::: "memory");
    if (cnt < NS && lane >= cnt && lane < NS) idx_out[q * NS + lane] = s_meta[wv][1];
    if (lane == 0) empty_out[q] = 0;
}

// ============ 3-pass MLP =====================================================
// PASS A (split-channel): 256 threads = 128 rows x 2 channel-halves.
// half is wave-uniform -> readfirstlane so weight loads stay SCALAR (s_load).
template <int NS, int CH, bool HALF>
__launch_bounds__(256, 6)
__global__ void mlp_passA_kernel(const float* __restrict__ xyz, const float* __restrict__ feats,
                                 const float* __restrict__ newxyz, const float* __restrict__ W0,
                                 void* __restrict__ xout_) {
    constexpr int GSTR = 37;        // gather row stride (35 used)
    constexpr int SST  = CH + 2;    // stats/store transpose stride
    constexpr int CHH  = CH / 2;    // channels per thread
    __shared__ float buf[128 * GSTR];   // 18.9 KB; reused for transpose
    __shared__ float ls[256], lq[256];
    int tid = threadIdx.x;
    int row = tid & 127, half = tid >> 7;
    int halfu = __builtin_amdgcn_readfirstlane(half);   // SGPR: waves are 64 threads
    int rowbase = blockIdx.x * 128;
    int grow = rowbase + row;
    int q = grow / NS, b = q >> 12;
    const int* idx_arr = (NS == SP) ? g_idx_p : g_idx_d;
    const int* emp_arr = (NS == SP) ? g_empty_p : g_empty_d;
    {
        float* dst = &buf[row * GSTR];
        if (emp_arr[q]) {
            int c0 = half ? 18 : 0, c1 = half ? 35 : 18;
            for (int c = c0; c < c1; ++c) dst[c] = 0.f;
        } else {
            int idx = idx_arr[grow];
            if (half == 0) {
                const float* xp = xyz + (size_t)b * NPTS * 3 + idx * 3;
                dst[0] = xp[0] - newxyz[q * 3 + 0];
                dst[1] = xp[1] - newxyz[q * 3 + 1];
                dst[2] = xp[2] - newxyz[q * 3 + 2];
            }
            const float4* fp = (const float4*)(feats + (size_t)b * NPTS * CIN + (size_t)idx * CIN);
#pragma unroll
            for (int j = 0; j < 4; ++j) {
                float4 v = fp[half * 4 + j];
                float* d = dst + 3 + (half * 4 + j) * 4;
                d[0] = v.x; d[1] = v.y; d[2] = v.z; d[3] = v.w;
            }
        }
    }
    __syncthreads();    // row written by 2 threads
    float acc[CHH];
#pragma unroll
    for (int ch = 0; ch < CHH; ++ch) acc[ch] = 0.f;
    {
        const float* inrow = &buf[row * GSTR];
        const float* w = W0 + halfu * CHH;          // SGPR base -> s_load weights
        for (int c = 0; c < 35; ++c) {
            float h = inrow[c];
#pragma unroll
            for (int ch = 0; ch < CHH; ++ch) acc[ch] = fmaf(h, w[c * CH + ch], acc[ch]);
        }
    }
    // stats + coalesced store via 2-pass LDS transpose (64 rows/pass)
    float* xf = (float*)xout_;
    __half* xh = (__half*)xout_;
    float sum = 0.f, sq = 0.f;
#pragma unroll
    for (int p = 0; p < 2; ++p) {
        __syncthreads();
        if ((row >> 6) == p) {
            float* srow = &buf[(row & 63) * SST + half * CHH];
#pragma unroll
            for (int ch = 0; ch < CHH; ++ch) srow[ch] = acc[ch];
        }
        __syncthreads();
        if (CH == 64) {
            int ch = tid & 63, rg = tid >> 6;
            for (int r = 0; r < 16; ++r) {
                float v = buf[(rg * 16 + r) * SST + ch];
                size_t o = (size_t)(rowbase + p * 64 + rg * 16 + r) * CH + ch;
                if (HALF) xh[o] = __float2half_rn(v); else xf[o] = v;
                sum += v; sq += v * v;
            }
        } else {
            int ch = tid & 31, rg = tid >> 5;
            for (int r = 0; r < 8; ++r) {
                float v = buf[(rg * 8 + r) * SST + ch];
                size_t o = (size_t)(rowbase + p * 64 + rg * 8 + r) * CH + ch;
                if (HALF) xh[o] = __float2half_rn(v); else xf[o] = v;
                sum += v; sq += v * v;
            }
        }
    }
    ls[tid] = sum; lq[tid] = sq;
    __syncthreads();
    if (CH == 64) {
        if (tid < 64) {
            g_psT[tid * 2048 + blockIdx.x] = ls[tid] + ls[64 + tid] + ls[128 + tid] + ls[192 + tid];
            g_pqT[tid * 2048 + blockIdx.x] = lq[tid] + lq[64 + tid] + lq[128 + tid] + lq[192 + tid];
        }
    } else {
        if (tid < 32) {
            float s = 0.f, qq = 0.f;
#pragma unroll
            for (int k = 0; k < 8; ++k) { s += ls[tid + 32 * k]; qq += lq[tid + 32 * k]; }
            g_psT[tid * 2048 + blockIdx.x] = s;
            g_pqT[tid * 2048 + blockIdx.x] = qq;
        }
    }
}

// PASS B (p-branch, fp32): stream x0p -> BN0+ReLU -> L1 -> store x1p + stats
template <int NS, int CH>
__launch_bounds__(128, 4)
__global__ void mlp_passB_kernel(const float* __restrict__ W1, const float* __restrict__ xin,
                                 float* __restrict__ xout, int bn0) {
    constexpr int HSTR = 33;
    constexpr int SST  = CH + 2;
    __shared__ float buf[128 * 37];
    __shared__ float ls[128], lq[128];
    int tid = threadIdx.x;
    int rowbase = blockIdx.x * 128;
    const float* sc0 = g_bnscale[bn0];
    const float* sh0 = g_bnshift[bn0];
    float acc2[CH];
#pragma unroll
    for (int ch = 0; ch < CH; ++ch) acc2[ch] = 0.f;
    const float4* src = (const float4*)xin;
#pragma unroll
    for (int hc = 0; hc < CH / 32; ++hc) {
        if (hc) __syncthreads();
#pragma unroll
        for (int k = 0; k < 8; ++k) {
            int o4 = tid + k * 128;       // 0..1023
            int rloc = o4 >> 3, j = o4 & 7;
            int c = 4 * j, gc = hc * 32 + c;
            float4 v = src[(size_t)(rowbase + rloc) * (CH / 4) + hc * 8 + j];
            float* d = &buf[rloc * HSTR + c];
            d[0] = fmaxf(fmaf(v.x, sc0[gc + 0], sh0[gc + 0]), 0.f);
            d[1] = fmaxf(fmaf(v.y, sc0[gc + 1], sh0[gc + 1]), 0.f);
            d[2] = fmaxf(fmaf(v.z, sc0[gc + 2], sh0[gc + 2]), 0.f);
            d[3] = fmaxf(fmaf(v.w, sc0[gc + 3], sh0[gc + 3]), 0.f);
        }
        __syncthreads();
        const float* hrow = &buf[tid * HSTR];
        for (int c = 0; c < 32; ++c) {
            float h = hrow[c];
#pragma unroll
            for (int ch = 0; ch < CH; ++ch)
                acc2[ch] = fmaf(h, W1[(hc * 32 + c) * CH + ch], acc2[ch]);
        }
    }
    float sum = 0.f, sq = 0.f;
#pragma unroll
    for (int p = 0; p < 2; ++p) {
        __syncthreads();
        if ((tid >> 6) == p) {
            float* srow = &buf[(tid & 63) * SST];
#pragma unroll
            for (int ch = 0; ch < CH; ++ch) srow[ch] = acc2[ch];
        }
        __syncthreads();
        int ch = tid & 31, rg = tid >> 5;
        for (int r = 0; r < 16; ++r) {
            float v = buf[(rg * 16 + r) * SST + ch];
            xout[(size_t)(rowbase + p * 64 + rg * 16 + r) * CH + ch] = v;
            sum += v; sq += v * v;
        }
    }
    ls[tid] = sum; lq[tid] = sq;
    __syncthreads();
    if (tid < 32) {
        g_psT[tid * 2048 + blockIdx.x] = ls[tid] + ls[32 + tid] + ls[64 + tid] + ls[96 + tid];
        g_pqT[tid * 2048 + blockIdx.x] = lq[tid] + lq[32 + tid] + lq[64 + tid] + lq[96 + tid];
    }
}

// PASS B (f-branch, fp16, split-channel): 256 threads = 128 rows x 2 halves;
// readfirstlane keeps W1 loads scalar; dot2 inner loop; coalesced store.
__launch_bounds__(256, 6)
__global__ void mlp_fB_kernel(const __half* __restrict__ xin, __half* __restrict__ xout) {
    __shared__ unsigned int hp[128 * 33];   // 16.9 KB; aliased as float [64][66]
    __shared__ float ls[256], lq[256];
    int tid = threadIdx.x;
    int row = tid & 127, half = tid >> 7;
    int halfu = __builtin_amdgcn_readfirstlane(half);   // SGPR
    int rowbase = blockIdx.x * 128;
    const float* sc0 = g_bnscale[2];
    const float* sh0 = g_bnshift[2];
    {
        const float4* src = (const float4*)xin;
#pragma unroll
        for (int k = 0; k < 4; ++k) {
            int o4 = tid + k * 256;       // 0..1023
            int rloc = o4 >> 3, j = o4 & 7;
            float4 v = src[(size_t)(rowbase + rloc) * 8 + j];
            const __half2* ph = (const __half2*)&v;   // 4 half2 pairs
            unsigned int* d = &hp[rloc * 33 + 4 * j];
#pragma unroll
            for (int m = 0; m < 4; ++m) {
                float2 f = __half22float2(ph[m]);
                int gc = 8 * j + 2 * m;
                float a = fmaxf(fmaf(f.x, sc0[gc + 0], sh0[gc + 0]), 0.f);
                float bb = fmaxf(fmaf(f.y, sc0[gc + 1], sh0[gc + 1]), 0.f);
                __half2 hh = __floats2half2_rn(a, bb);
                d[m] = *(unsigned int*)&hh;
            }
        }
    }
    __syncthreads();
    float acc[32];
#pragma unroll
    for (int ch = 0; ch < 32; ++ch) acc[ch] = 0.f;
    {
        const unsigned int* hrow = &hp[row * 33];
        const unsigned int* wbase = g_w1h + (halfu * 32) * 32;   // SGPR base -> s_load
#pragma unroll
        for (int c2 = 0; c2 < 32; ++c2) {
            unsigned int h2 = hrow[c2];
#pragma unroll
            for (int ch = 0; ch < 32; ++ch)
                acc[ch] = fdot2f(h2, wbase[ch * 32 + c2], acc[ch]);
        }
    }
    // transpose: coalesced half store + stats from same LDS pass
    float* fview = (float*)hp;              // [64][66] = 4224 floats, exact fit
    float sum = 0.f, sq = 0.f;
#pragma unroll
    for (int p = 0; p < 2; ++p) {
        __syncthreads();
        if ((row >> 6) == p) {
            float* srow = &fview[(row & 63) * 66 + half * 32];
#pragma unroll
            for (int ch = 0; ch < 32; ++ch) srow[ch] = acc[ch];
        }
        __syncthreads();
        int ch = tid & 63, rg = tid >> 6;
        for (int r = 0; r < 16; ++r) {
            float v = fview[(rg * 16 + r) * 66 + ch];
            xout[(size_t)(rowbase + p * 64 + rg * 16 + r) * CF + ch] = __float2half_rn(v);
            sum += v; sq += v * v;
        }
    }
    ls[tid] = sum; lq[tid] = sq;
    __syncthreads();
    if (tid < 64) {
        g_psT[tid * 2048 + blockIdx.x] = ls[tid] + ls[64 + tid] + ls[128 + tid] + ls[192 + tid];
        g_pqT[tid * 2048 + blockIdx.x] = lq[tid] + lq[64 + tid] + lq[128 + tid] + lq[192 + tid];
    }
}

// -------- BN stats finalize: one block per channel, coalesced, tree-reduce --
__global__ void finalize_kernel(const float* __restrict__ gamma, const float* __restrict__ beta,
                                float n, int layer, int nblocks) {
    __shared__ double l_s[256], l_q[256];
    int ch = blockIdx.x, tid = threadIdx.x;
    double s = 0, q = 0;
    for (int i = tid; i < nblocks; i += 256) { s += g_psT[ch * 2048 + i]; q += g_pqT[ch * 2048 + i]; }
    l_s[tid] = s; l_q[tid] = q; __syncthreads();
    for (int off = 128; off > 0; off >>= 1) {
        if (tid < off) { l_s[tid] += l_s[tid + off]; l_q[tid] += l_q[tid + off]; }
        __syncthreads();
    }
    if (tid == 0) {
        double mu = l_s[0] / (double)n;
        double var = l_q[0] / (double)n - mu * mu;
        if (var < 0) var = 0;
        double sc = (double)gamma[ch] / sqrt(var + 1e-5);
        g_bnscale[layer][ch] = (float)sc;
        g_bnshift[layer][ch] = (float)((double)beta[ch] - mu * sc);
    }
}

// PASS C deform: stream x1f (fp16), BN1+ReLU, sigmoid weight, max over 32 -> out
__global__ void passC_f_kernel(const float* __restrict__ xyz, const float* __restrict__ newxyz,
                               const float* __restrict__ td, const __half* __restrict__ xin,
                               float* __restrict__ out) {
    __shared__ float lw[64];
    int tid = threadIdx.x;
    int qpair = blockIdx.x * 2;
    if (tid < 64) {
        int ql = tid >> 5, s = tid & 31;
        int q = qpair + ql;
        float wv = 0.f;
        if (!g_empty_d[q]) {
            int idx = g_idx_d[q * SD + s];
            int b = q >> 12;
            float dx = xyz[(size_t)b * NPTS * 3 + idx * 3 + 0] - newxyz[q * 3 + 0];
            float dy = xyz[(size_t)b * NPTS * 3 + idx * 3 + 1] - newxyz[q * 3 + 1];
            float dz = xyz[(size_t)b * NPTS * 3 + idx * 3 + 2] - newxyz[q * 3 + 2];
            float dist = sqrtf(dx * dx + dy * dy + dz * dz);
            float rq = g_rroi[q >> 6];
            wv = 1.f / (1.f + expf(-(rq - dist) / td[0]));
        }
        lw[tid] = wv;
    }
    __syncthreads();
    int ql = tid >> 6, ch = tid & 63;
    int q = qpair + ql;
    float sc = g_bnscale[3][ch], sh = g_bnshift[3][ch];
    float m = 0.f;
    for (int s = 0; s < SD; ++s) {
        float v = __half2float(xin[((size_t)q * SD + s) * CF + ch]);
        m = fmaxf(m, lw[ql * 32 + s] * fmaxf(fmaf(v, sc, sh), 0.f));
    }
    out[MTOT * 3 + (size_t)q * CF + ch] = m;
}

// PASS C pred fused with per-roi fc reduce: one block per roi
__global__ void passC_roi_kernel(const float* __restrict__ fcw, const float* __restrict__ fcb,
                                 const float* __restrict__ roif, const float* __restrict__ xin) {
    __shared__ float red[256];
    int tid = threadIdx.x;
    int roi = blockIdx.x;
    int ch = tid & 31, qs = tid >> 5;
    float sc = g_bnscale[1][ch], sh = g_bnshift[1][ch];
    float acc = 0.f;
    for (int ql = qs; ql < 64; ql += 8) {
        int q = roi * 64 + ql;
        float m = 0.f;
        for (int s = 0; s < SP; ++s) {
            float v = xin[(size_t)(q * SP + s) * CP + ch] * sc + sh;
            m = fmaxf(m, fmaxf(v, 0.f));
        }
        acc += m * fcw[ql * CP + ch];
    }
    if (tid < 128) acc += roif[roi * 128 + tid] * fcw[2048 + tid];
    red[tid] = acc;
    __syncthreads();
    for (int off = 128; off > 0; off >>= 1) {
        if (tid < off) red[tid] += red[tid + off];
        __syncthreads();
    }
    if (tid == 0)
        g_rroi[roi] = fmaxf((red[0] + fcb[0]) / DIV_COEF_C + RADIUS_C, MIN_R_C);
}

extern "C" void kernel_launch(void* const* d_in, const int* in_sizes, int n_in,
                              void* d_out, int out_size, void* d_ws, size_t ws_size,
                              hipStream_t stream) {
    const float* xyz   = (const float*)d_in[0];
    const float* feats = (const float*)d_in[1];
    const float* rois  = (const float*)d_in[2];
    const float* roif  = (const float*)d_in[3];
    const float* td    = (const float*)d_in[4];
    const float* pw0 = (const float*)d_in[5];
    const float* pg0 = (const float*)d_in[6];
    const float* pb0 = (const float*)d_in[7];
    const float* pw1 = (const float*)d_in[8];
    const float* pg1 = (const float*)d_in[9];
    const float* pb1 = (const float*)d_in[10];
    const float* fw0 = (const float*)d_in[11];
    const float* fg0 = (const float*)d_in[12];
    const float* fb0 = (const float*)d_in[13];
    const float* fw1 = (const float*)d_in[14];
    const float* fg1 = (const float*)d_in[15];
    const float* fb1 = (const float*)d_in[16];
    const float* fcw = (const float*)d_in[17];
    const float* fcb = (const float*)d_in[18];
    float* out = (float*)d_out;

    void* xa; hipGetSymbolAddress(&xa, HIP_SYMBOL(g_xa));
    void* xb; hipGetSymbolAddress(&xb, HIP_SYMBOL(g_xb));

    setup_kernel<<<(SETUP_N + 255) / 256, 256, 0, stream>>>(rois, fw1, out);
    grid_count_kernel<<<64, 256, 0, stream>>>(xyz);
    grid_prefix_kernel<<<2, 1024, 0, stream>>>();
    grid_scatter_kernel<<<64, 256, 0, stream>>>(xyz);

    // pred branch (16 samples, 32 ch, all fp32)
    bq_grid_kernel<SP><<<MTOT / 4, 256, 0, stream>>>(xyz, rois);
    mlp_passA_kernel<SP, CP, false><<<1024, 256, 0, stream>>>(xyz, feats, rois, pw0, xa);
    finalize_kernel<<<CP, 256, 0, stream>>>(pg0, pb0, (float)(MTOT * SP), 0, 1024);
    mlp_passB_kernel<SP, CP><<<1024, 128, 0, stream>>>(pw1, (const float*)xa, (float*)xb, 0);
    finalize_kernel<<<CP, 256, 0, stream>>>(pg1, pb1, (float)(MTOT * SP), 1, 1024);
    passC_roi_kernel<<<NROI, 256, 0, stream>>>(fcw, fcb, roif, (const float*)xb);

    // deform branch (32 samples, 64 ch, fp16 intermediates)
    bq_grid_kernel<SD><<<MTOT / 4, 256, 0, stream>>>(xyz, rois);
    mlp_passA_kernel<SD, CF, true><<<2048, 256, 0, stream>>>(xyz, feats, rois, fw0, xa);
    finalize_kernel<<<CF, 256, 0, stream>>>(fg0, fb0, (float)(MTOT * SD), 2, 2048);
    mlp_fB_kernel<<<2048, 256, 0, stream>>>((const __half*)xa, (__half*)xb);
    finalize_kernel<<<CF, 256, 0, stream>>>(fg1, fb1, (float)(MTOT * SD), 3, 2048);
    passC_f_kernel<<<MTOT / 2, 128, 0, stream>>>(xyz, rois, td, (const __half*)xb, out);
}

// Round 12
// 251.942 us; speedup vs baseline: 1.5082x; 1.0826x over previous
//
#include <hip/hip_runtime.h>
#include <hip/hip_fp16.h>

#define NB 2
#define NPTS 8192
#define NQ 4096
#define MTOT 8192      // NB*NQ
#define SP 16
#define SD 32
#define CIN 32
#define CP 32
#define CF 64
#define NROI 128       // NB*64
#define RADIUS_C 0.8f
#define MIN_R_C 0.01f
#define DIV_COEF_C 10.0f

// ---- spatial grid (cell = radius = 0.8; scene = [10,10,4]) ----------------
#define INV_CS 1.25f
#define NCX 13
#define NCY 13
#define NCZ 5
#define NCELL (NCX * NCY * NCZ)   // 845

// ---------------- device-global scratch (fully rewritten every call) -------
__device__ int    g_idx_p[MTOT * SP];
__device__ int    g_empty_p[MTOT];
__device__ int    g_idx_d[MTOT * SD];
__device__ int    g_empty_d[MTOT];
__device__ int    g_cellcnt[NB][NCELL];
__device__ int    g_cellcur[NB][NCELL];
__device__ int    g_cellstart[NB][NCELL + 1];
__device__ float4 g_cellxyzw[NB][NPTS];   // packed (x,y,z,index) per reordered point
// activation buffers: p-branch fp32 (16.7MB), f-branch fp16 (33.5MB)
__device__ unsigned char g_xa[(size_t)MTOT * SD * CF * 2];
__device__ unsigned char g_xb[(size_t)MTOT * SD * CF * 2];
__device__ unsigned int g_w1h[CF * CF / 2];       // W1 as half2 k-pairs: [ch][c2]
__device__ float  g_psT[CF * 2048];               // BN partials, transposed [ch][block]
__device__ float  g_pqT[CF * 2048];
__device__ float  g_bnscale[4][CF];               // 0=p0 1=p1 2=f0 3=f1
__device__ float  g_bnshift[4][CF];
__device__ float  g_rroi[NROI];

typedef _Float16 h2v  __attribute__((ext_vector_type(2)));
typedef _Float16 f16x8 __attribute__((ext_vector_type(8)));
typedef float    f32x4 __attribute__((ext_vector_type(4)));

__device__ __forceinline__ int cell_of(float x, float y, float z) {
    int cx = min(NCX - 1, max(0, (int)floorf(x * INV_CS)));
    int cy = min(NCY - 1, max(0, (int)floorf(y * INV_CS)));
    int cz = min(NCZ - 1, max(0, (int)floorf(z * INV_CS)));
    return (cz * NCY + cy) * NCX + cx;
}

// ====== setup: xyz copy + W1 pack + cellcnt zero ===========================
#define SETUP_N (MTOT * 3 + CF * CF / 2 + NB * NCELL)
__global__ void setup_kernel(const float* __restrict__ rois, const float* __restrict__ fw1,
                             float* __restrict__ out) {
    int i = blockIdx.x * 256 + threadIdx.x;
    if (i < MTOT * 3) { out[i] = rois[i]; return; }
    i -= MTOT * 3;
    if (i < CF * CF / 2) {
        int ch = i >> 5, c2 = i & 31;
        __half2 h = __floats2half2_rn(fw1[(2 * c2) * CF + ch], fw1[(2 * c2 + 1) * CF + ch]);
        g_w1h[i] = *(unsigned int*)&h;
        return;
    }
    i -= CF * CF / 2;
    if (i < NB * NCELL) ((int*)g_cellcnt)[i] = 0;
}

// ================= grid build (shared by both bq phases) ====================
__global__ void grid_count_kernel(const float* __restrict__ xyz) {
    int i = blockIdx.x * 256 + threadIdx.x;   // 0..16383
    int b = i >> 13;
    int cell = cell_of(xyz[(size_t)i * 3 + 0], xyz[(size_t)i * 3 + 1], xyz[(size_t)i * 3 + 2]);
    atomicAdd(&g_cellcnt[b][cell], 1);
}

__global__ void grid_prefix_kernel() {     // one block per batch
    __shared__ int sc[1024];
    int b = blockIdx.x, tid = threadIdx.x;
    int v = (tid < NCELL) ? g_cellcnt[b][tid] : 0;
    sc[tid] = v;
    __syncthreads();
    for (int off = 1; off < 1024; off <<= 1) {
        int add = (tid >= off) ? sc[tid - off] : 0;
        __syncthreads();
        sc[tid] += add;
        __syncthreads();
    }
    if (tid < NCELL) {
        int excl = sc[tid] - v;
        g_cellstart[b][tid] = excl;
        g_cellcur[b][tid] = excl;
    }
    if (tid == 0) g_cellstart[b][NCELL] = NPTS;
}

__global__ void grid_scatter_kernel(const float* __restrict__ xyz) {
    int i = blockIdx.x * 256 + threadIdx.x;
    int b = i >> 13, il = i & (NPTS - 1);
    float x = xyz[(size_t)i * 3 + 0];
    float y = xyz[(size_t)i * 3 + 1];
    float z = xyz[(size_t)i * 3 + 2];
    int cell = cell_of(x, y, z);
    int pos = atomicAdd(&g_cellcur[b][cell], 1);
    g_cellxyzw[b][pos] = make_float4(x, y, z, __int_as_float(il));
}

// ======= ball query: wave/query; LDS candidate append + rank-by-count ======
template <int NS>
__launch_bounds__(256, 8)
__global__ void bq_grid_kernel(const float* __restrict__ xyz, const float* __restrict__ newxyz) {
    __shared__ int s_cand[4][512];
    __shared__ int s_meta[4][2];   // [0]=count, [1]=min element
    int tid = threadIdx.x, wv = tid >> 6, lane = tid & 63;
    int q = blockIdx.x * 4 + wv;
    int b = q >> 12;
    float qx = newxyz[q * 3 + 0], qy = newxyz[q * 3 + 1], qz = newxyz[q * 3 + 2];
    float r = (NS == SP) ? RADIUS_C : g_rroi[q >> 6];
    float r2 = r * r;
    int* idx_out   = (NS == SP) ? g_idx_p   : g_idx_d;
    int* empty_out = (NS == SP) ? g_empty_p : g_empty_d;

    if (lane == 0) s_meta[wv][0] = 0;
    __asm__ volatile("s_waitcnt lgkmcnt(0)" ::: "memory");

    float rp = r + 1e-4f;
    int xlo = max(0, min(NCX - 1, (int)floorf((qx - rp) * INV_CS)));
    int xhi = max(0, min(NCX - 1, (int)floorf((qx + rp) * INV_CS)));
    int ylo = max(0, min(NCY - 1, (int)floorf((qy - rp) * INV_CS)));
    int yhi = max(0, min(NCY - 1, (int)floorf((qy + rp) * INV_CS)));
    int zlo = max(0, min(NCZ - 1, (int)floorf((qz - rp) * INV_CS)));
    int zhi = max(0, min(NCZ - 1, (int)floorf((qz + rp) * INV_CS)));
    int nx = xhi - xlo + 1, ny = yhi - ylo + 1, nz = zhi - zlo + 1;
    int ncell = nx * ny * nz;

    bool ovf = false;
    for (int ci = lane; ci < ncell; ci += 64) {
        int cx = xlo + (ci % nx);
        int t1 = ci / nx;
        int cy = ylo + (t1 % ny);
        int cz = zlo + (t1 / ny);
        int cell = (cz * NCY + cy) * NCX + cx;
        int s0 = g_cellstart[b][cell], e0 = g_cellstart[b][cell + 1];
        for (int e = s0; e < e0; ++e) {
            float4 v = g_cellxyzw[b][e];
            float dx = qx - v.x, dy = qy - v.y, dz = qz - v.z;
            if (dx * dx + dy * dy + dz * dz < r2) {
                int pos = atomicAdd(&s_meta[wv][0], 1);
                if (pos < 512) s_cand[wv][pos] = __float_as_int(v.w);
                else ovf = true;
            }
        }
    }
    __asm__ volatile("s_waitcnt lgkmcnt(0) vmcnt(0)" ::: "memory");
    int cnt = s_meta[wv][0];

    if (__ballot(ovf)) {   // rare: >512 in-ball — original ordered full scan
        const float* xb = xyz + (size_t)b * NPTS * 3;
        int cnt2 = 0, first_idx = 0;
        for (int g = 0; g < NPTS / 64 && cnt2 < NS; ++g) {
            int p = (g << 6) + lane;
            float dx = qx - xb[3 * p + 0];
            float dy = qy - xb[3 * p + 1];
            float dz = qz - xb[3 * p + 2];
            bool valid = (dx * dx + dy * dy + dz * dz) < r2;
            unsigned long long mask = __ballot(valid);
            if (cnt2 == 0 && mask) first_idx = (g << 6) + (int)__builtin_ctzll(mask);
            int pos = cnt2 + __popcll(mask & ((1ull << lane) - 1ull));
            if (valid && pos < NS) idx_out[q * NS + pos] = p;
            cnt2 += (int)__popcll(mask);
        }
        if (cnt2 == 0) {
            if (lane < NS) idx_out[q * NS + lane] = 0;
            if (lane == 0) empty_out[q] = 1;
        } else {
            int filled = cnt2 < NS ? cnt2 : NS;
            if (lane >= filled && lane < NS) idx_out[q * NS + lane] = first_idx;
            if (lane == 0) empty_out[q] = 0;
        }
        return;
    }

    if (cnt == 0) {
        if (lane < NS) idx_out[q * NS + lane] = 0;
        if (lane == 0) empty_out[q] = 1;
        return;
    }
    // rank-by-count: j-loop reads are wave-uniform -> LDS broadcast (free)
    for (int i = lane; i < cnt; i += 64) {
        int c = s_cand[wv][i];
        int rank = 0;
        for (int j = 0; j < cnt; ++j) rank += (s_cand[wv][j] < c) ? 1 : 0;
        if (rank < NS) idx_out[q * NS + rank] = c;
        if (rank == 0) s_meta[wv][1] = c;
    }
    __asm__ volatile("s_waitcnt lgkmcnt(0)" ::: "memory");
    if (cnt < NS && lane >= cnt && lane < NS) idx_out[q * NS + lane] = s_meta[wv][1];
    if (lane == 0) empty_out[q] = 0;
}

// ============ 3-pass MLP =====================================================
// PASS A (split-channel): 256 threads = 128 rows x 2 channel-halves.
// half is wave-uniform -> readfirstlane so weight loads stay SCALAR (s_load).
template <int NS, int CH, bool HALF>
__launch_bounds__(256, 6)
__global__ void mlp_passA_kernel(const float* __restrict__ xyz, const float* __restrict__ feats,
                                 const float* __restrict__ newxyz, const float* __restrict__ W0,
                                 void* __restrict__ xout_) {
    constexpr int GSTR = 37;        // gather row stride (35 used)
    constexpr int SST  = CH + 2;    // stats/store transpose stride
    constexpr int CHH  = CH / 2;    // channels per thread
    __shared__ float buf[128 * GSTR];   // 18.9 KB; reused for transpose
    __shared__ float ls[256], lq[256];
    int tid = threadIdx.x;
    int row = tid & 127, half = tid >> 7;
    int halfu = __builtin_amdgcn_readfirstlane(half);   // SGPR: waves are 64 threads
    int rowbase = blockIdx.x * 128;
    int grow = rowbase + row;
    int q = grow / NS, b = q >> 12;
    const int* idx_arr = (NS == SP) ? g_idx_p : g_idx_d;
    const int* emp_arr = (NS == SP) ? g_empty_p : g_empty_d;
    {
        float* dst = &buf[row * GSTR];
        if (emp_arr[q]) {
            int c0 = half ? 18 : 0, c1 = half ? 35 : 18;
            for (int c = c0; c < c1; ++c) dst[c] = 0.f;
        } else {
            int idx = idx_arr[grow];
            if (half == 0) {
                const float* xp = xyz + (size_t)b * NPTS * 3 + idx * 3;
                dst[0] = xp[0] - newxyz[q * 3 + 0];
                dst[1] = xp[1] - newxyz[q * 3 + 1];
                dst[2] = xp[2] - newxyz[q * 3 + 2];
            }
            const float4* fp = (const float4*)(feats + (size_t)b * NPTS * CIN + (size_t)idx * CIN);
#pragma unroll
            for (int j = 0; j < 4; ++j) {
                float4 v = fp[half * 4 + j];
                float* d = dst + 3 + (half * 4 + j) * 4;
                d[0] = v.x; d[1] = v.y; d[2] = v.z; d[3] = v.w;
            }
        }
    }
    __syncthreads();    // row written by 2 threads
    float acc[CHH];
#pragma unroll
    for (int ch = 0; ch < CHH; ++ch) acc[ch] = 0.f;
    {
        const float* inrow = &buf[row * GSTR];
        const float* w = W0 + halfu * CHH;          // SGPR base -> s_load weights
        for (int c = 0; c < 35; ++c) {
            float h = inrow[c];
#pragma unroll
            for (int ch = 0; ch < CHH; ++ch) acc[ch] = fmaf(h, w[c * CH + ch], acc[ch]);
        }
    }
    // stats + coalesced store via 2-pass LDS transpose (64 rows/pass)
    float* xf = (float*)xout_;
    __half* xh = (__half*)xout_;
    float sum = 0.f, sq = 0.f;
#pragma unroll
    for (int p = 0; p < 2; ++p) {
        __syncthreads();
        if ((row >> 6) == p) {
            float* srow = &buf[(row & 63) * SST + half * CHH];
#pragma unroll
            for (int ch = 0; ch < CHH; ++ch) srow[ch] = acc[ch];
        }
        __syncthreads();
        if (CH == 64) {
            int ch = tid & 63, rg = tid >> 6;
            for (int r = 0; r < 16; ++r) {
                float v = buf[(rg * 16 + r) * SST + ch];
                size_t o = (size_t)(rowbase + p * 64 + rg * 16 + r) * CH + ch;
                if (HALF) xh[o] = __float2half_rn(v); else xf[o] = v;
                sum += v; sq += v * v;
            }
        } else {
            int ch = tid & 31, rg = tid >> 5;
            for (int r = 0; r < 8; ++r) {
                float v = buf[(rg * 8 + r) * SST + ch];
                size_t o = (size_t)(rowbase + p * 64 + rg * 8 + r) * CH + ch;
                if (HALF) xh[o] = __float2half_rn(v); else xf[o] = v;
                sum += v; sq += v * v;
            }
        }
    }
    ls[tid] = sum; lq[tid] = sq;
    __syncthreads();
    if (CH == 64) {
        if (tid < 64) {
            g_psT[tid * 2048 + blockIdx.x] = ls[tid] + ls[64 + tid] + ls[128 + tid] + ls[192 + tid];
            g_pqT[tid * 2048 + blockIdx.x] = lq[tid] + lq[64 + tid] + lq[128 + tid] + lq[192 + tid];
        }
    } else {
        if (tid < 32) {
            float s = 0.f, qq = 0.f;
#pragma unroll
            for (int k = 0; k < 8; ++k) { s += ls[tid + 32 * k]; qq += lq[tid + 32 * k]; }
            g_psT[tid * 2048 + blockIdx.x] = s;
            g_pqT[tid * 2048 + blockIdx.x] = qq;
        }
    }
}

// PASS B (p-branch, fp32): stream x0p -> BN0+ReLU -> L1 -> store x1p + stats
template <int NS, int CH>
__launch_bounds__(128, 4)
__global__ void mlp_passB_kernel(const float* __restrict__ W1, const float* __restrict__ xin,
                                 float* __restrict__ xout, int bn0) {
    constexpr int HSTR = 33;
    constexpr int SST  = CH + 2;
    __shared__ float buf[128 * 37];
    __shared__ float ls[128], lq[128];
    int tid = threadIdx.x;
    int rowbase = blockIdx.x * 128;
    const float* sc0 = g_bnscale[bn0];
    const float* sh0 = g_bnshift[bn0];
    float acc2[CH];
#pragma unroll
    for (int ch = 0; ch < CH; ++ch) acc2[ch] = 0.f;
    const float4* src = (const float4*)xin;
#pragma unroll
    for (int hc = 0; hc < CH / 32; ++hc) {
        if (hc) __syncthreads();
#pragma unroll
        for (int k = 0; k < 8; ++k) {
            int o4 = tid + k * 128;       // 0..1023
            int rloc = o4 >> 3, j = o4 & 7;
            int c = 4 * j, gc = hc * 32 + c;
            float4 v = src[(size_t)(rowbase + rloc) * (CH / 4) + hc * 8 + j];
            float* d = &buf[rloc * HSTR + c];
            d[0] = fmaxf(fmaf(v.x, sc0[gc + 0], sh0[gc + 0]), 0.f);
            d[1] = fmaxf(fmaf(v.y, sc0[gc + 1], sh0[gc + 1]), 0.f);
            d[2] = fmaxf(fmaf(v.z, sc0[gc + 2], sh0[gc + 2]), 0.f);
            d[3] = fmaxf(fmaf(v.w, sc0[gc + 3], sh0[gc + 3]), 0.f);
        }
        __syncthreads();
        const float* hrow = &buf[tid * HSTR];
        for (int c = 0; c < 32; ++c) {
            float h = hrow[c];
#pragma unroll
            for (int ch = 0; ch < CH; ++ch)
                acc2[ch] = fmaf(h, W1[(hc * 32 + c) * CH + ch], acc2[ch]);
        }
    }
    float sum = 0.f, sq = 0.f;
#pragma unroll
    for (int p = 0; p < 2; ++p) {
        __syncthreads();
        if ((tid >> 6) == p) {
            float* srow = &buf[(tid & 63) * SST];
#pragma unroll
            for (int ch = 0; ch < CH; ++ch) srow[ch] = acc2[ch];
        }
        __syncthreads();
        int ch = tid & 31, rg = tid >> 5;
        for (int r = 0; r < 16; ++r) {
            float v = buf[(rg * 16 + r) * SST + ch];
            xout[(size_t)(rowbase + p * 64 + rg * 16 + r) * CH + ch] = v;
            sum += v; sq += v * v;
        }
    }
    ls[tid] = sum; lq[tid] = sq;
    __syncthreads();
    if (tid < 32) {
        g_psT[tid * 2048 + blockIdx.x] = ls[tid] + ls[32 + tid] + ls[64 + tid] + ls[96 + tid];
        g_pqT[tid * 2048 + blockIdx.x] = lq[tid] + lq[32 + tid] + lq[64 + tid] + lq[96 + tid];
    }
}

// PASS B (f-branch, fp16, MFMA): 256 threads = 4 waves x 32 rows each.
// A = BN0+ReLU(x0f) packed as half2 k-pairs in LDS (row stride 36 u32, 16B-aligned);
// B = g_w1h k-pairs (exactly the 16x16x32_f16 B-fragment layout).
// D-fragment (col=lane&15, row=(lane>>4)*4+i) -> direct stores + shfl stats:
// no transpose pipeline, 2 barriers total.
__launch_bounds__(256, 4)
__global__ void mlp_fB_kernel(const __half* __restrict__ xin, __half* __restrict__ xout) {
    __shared__ __align__(16) unsigned int hp[128 * 36];   // 18.4 KB
    __shared__ float lsum[4][64], lsq[4][64];             // 2 KB
    int tid = threadIdx.x, wv = tid >> 6, lane = tid & 63;
    int rowbase = blockIdx.x * 128;
    const float* sc0 = g_bnscale[2];
    const float* sh0 = g_bnshift[2];
    // load + BN0+ReLU + pack half2 -> LDS rows (stride 36 u32 = 144 B)
    {
        const float4* src = (const float4*)xin;
#pragma unroll
        for (int k = 0; k < 4; ++k) {
            int o4 = tid + k * 256;       // 0..1023
            int rloc = o4 >> 3, j = o4 & 7;
            float4 v = src[(size_t)(rowbase + rloc) * 8 + j];
            const __half2* ph = (const __half2*)&v;   // 4 half2 pairs
            unsigned int* d = &hp[rloc * 36 + 4 * j];
#pragma unroll
            for (int m = 0; m < 4; ++m) {
                float2 f = __half22float2(ph[m]);
                int gc = 8 * j + 2 * m;
                float a = fmaxf(fmaf(f.x, sc0[gc + 0], sh0[gc + 0]), 0.f);
                float bb = fmaxf(fmaf(f.y, sc0[gc + 1], sh0[gc + 1]), 0.f);
                __half2 hh = __floats2half2_rn(a, bb);
                d[m] = *(unsigned int*)&hh;
            }
        }
    }
    // B fragments: lane needs W1[k=(lane>>4)*8+j][ct*16+(lane&15)], kt in {0,1}.
    // g_w1h[ch*32 + c2] = {W1[2c2][ch], W1[2c2+1][ch]} -> 4 consecutive u32 at
    // ch*32 + kt*16 + (lane>>4)*4. One-time 16B loads, L2-resident.
    f16x8 bf[4][2];
    {
        int chl = lane & 15, kg = lane >> 4;
#pragma unroll
        for (int ct = 0; ct < 4; ++ct)
#pragma unroll
            for (int kt = 0; kt < 2; ++kt)
                bf[ct][kt] = *(const f16x8*)(g_w1h + (ct * 16 + chl) * 32 + kt * 16 + kg * 4);
    }
    __syncthreads();
    f32x4 acc[2][4];
#pragma unroll
    for (int rt = 0; rt < 2; ++rt)
#pragma unroll
        for (int ct = 0; ct < 4; ++ct) acc[rt][ct] = (f32x4){0.f, 0.f, 0.f, 0.f};
#pragma unroll
    for (int rt = 0; rt < 2; ++rt) {
        int row = wv * 32 + rt * 16 + (lane & 15);
#pragma unroll
        for (int kt = 0; kt < 2; ++kt) {
            f16x8 a = *(const f16x8*)&hp[row * 36 + kt * 16 + (lane >> 4) * 4];
#pragma unroll
            for (int ct = 0; ct < 4; ++ct)
                acc[rt][ct] = __builtin_amdgcn_mfma_f32_16x16x32_f16(a, bf[ct][kt], acc[rt][ct], 0, 0, 0);
        }
    }
    // direct stores (lane&15 -> 32B-contiguous ch segments) + per-lane stats
    float s[4] = {0.f, 0.f, 0.f, 0.f}, q[4] = {0.f, 0.f, 0.f, 0.f};
#pragma unroll
    for (int rt = 0; rt < 2; ++rt) {
        int rbase = rowbase + wv * 32 + rt * 16 + (lane >> 4) * 4;
#pragma unroll
        for (int ct = 0; ct < 4; ++ct) {
            int ch = ct * 16 + (lane & 15);
#pragma unroll
            for (int i = 0; i < 4; ++i) {
                float v = acc[rt][ct][i];
                xout[(size_t)(rbase + i) * CF + ch] = __float2half_rn(v);
                s[ct] += v; q[ct] += v * v;
            }
        }
    }
    // reduce over the 4 lane-groups holding the same channel
#pragma unroll
    for (int ct = 0; ct < 4; ++ct) {
        s[ct] += __shfl_xor(s[ct], 16, 64); s[ct] += __shfl_xor(s[ct], 32, 64);
        q[ct] += __shfl_xor(q[ct], 16, 64); q[ct] += __shfl_xor(q[ct], 32, 64);
    }
    if (lane < 16) {
#pragma unroll
        for (int ct = 0; ct < 4; ++ct) {
            lsum[wv][ct * 16 + lane] = s[ct];
            lsq[wv][ct * 16 + lane] = q[ct];
        }
    }
    __syncthreads();
    if (tid < 64) {
        g_psT[tid * 2048 + blockIdx.x] = lsum[0][tid] + lsum[1][tid] + lsum[2][tid] + lsum[3][tid];
        g_pqT[tid * 2048 + blockIdx.x] = lsq[0][tid] + lsq[1][tid] + lsq[2][tid] + lsq[3][tid];
    }
}

// -------- BN stats finalize: one block per channel, coalesced, tree-reduce --
__global__ void finalize_kernel(const float* __restrict__ gamma, const float* __restrict__ beta,
                                float n, int layer, int nblocks) {
    __shared__ double l_s[256], l_q[256];
    int ch = blockIdx.x, tid = threadIdx.x;
    double s = 0, q = 0;
    for (int i = tid; i < nblocks; i += 256) { s += g_psT[ch * 2048 + i]; q += g_pqT[ch * 2048 + i]; }
    l_s[tid] = s; l_q[tid] = q; __syncthreads();
    for (int off = 128; off > 0; off >>= 1) {
        if (tid < off) { l_s[tid] += l_s[tid + off]; l_q[tid] += l_q[tid + off]; }
        __syncthreads();
    }
    if (tid == 0) {
        double mu = l_s[0] / (double)n;
        double var = l_q[0] / (double)n - mu * mu;
        if (var < 0) var = 0;
        double sc = (double)gamma[ch] / sqrt(var + 1e-5);
        g_bnscale[layer][ch] = (float)sc;
        g_bnshift[layer][ch] = (float)((double)beta[ch] - mu * sc);
    }
}

// PASS C deform: stream x1f (fp16), BN1+ReLU, sigmoid weight, max over 32 -> out
__global__ void passC_f_kernel(const float* __restrict__ xyz, const float* __restrict__ newxyz,
                               const float* __restrict__ td, const __half* __restrict__ xin,
                               float* __restrict__ out) {
    __shared__ float lw[64];
    int tid = threadIdx.x;
    int qpair = blockIdx.x * 2;
    if (tid < 64) {
        int ql = tid >> 5, s = tid & 31;
        int q = qpair + ql;
        float wv = 0.f;
        if (!g_empty_d[q]) {
            int idx = g_idx_d[q * SD + s];
            int b = q >> 12;
            float dx = xyz[(size_t)b * NPTS * 3 + idx * 3 + 0] - newxyz[q * 3 + 0];
            float dy = xyz[(size_t)b * NPTS * 3 + idx * 3 + 1] - newxyz[q * 3 + 1];
            float dz = xyz[(size_t)b * NPTS * 3 + idx * 3 + 2] - newxyz[q * 3 + 2];
            float dist = sqrtf(dx * dx + dy * dy + dz * dz);
            float rq = g_rroi[q >> 6];
            wv = 1.f / (1.f + expf(-(rq - dist) / td[0]));
        }
        lw[tid] = wv;
    }
    __syncthreads();
    int ql = tid >> 6, ch = tid & 63;
    int q = qpair + ql;
    float sc = g_bnscale[3][ch], sh = g_bnshift[3][ch];
    float m = 0.f;
    for (int s = 0; s < SD; ++s) {
        float v = __half2float(xin[((size_t)q * SD + s) * CF + ch]);
        m = fmaxf(m, lw[ql * 32 + s] * fmaxf(fmaf(v, sc, sh), 0.f));
    }
    out[MTOT * 3 + (size_t)q * CF + ch] = m;
}

// PASS C pred fused with per-roi fc reduce: one block per roi
__global__ void passC_roi_kernel(const float* __restrict__ fcw, const float* __restrict__ fcb,
                                 const float* __restrict__ roif, const float* __restrict__ xin) {
    __shared__ float red[256];
    int tid = threadIdx.x;
    int roi = blockIdx.x;
    int ch = tid & 31, qs = tid >> 5;
    float sc = g_bnscale[1][ch], sh = g_bnshift[1][ch];
    float acc = 0.f;
    for (int ql = qs; ql < 64; ql += 8) {
        int q = roi * 64 + ql;
        float m = 0.f;
        for (int s = 0; s < SP; ++s) {
            float v = xin[(size_t)(q * SP + s) * CP + ch] * sc + sh;
            m = fmaxf(m, fmaxf(v, 0.f));
        }
        acc += m * fcw[ql * CP + ch];
    }
    if (tid < 128) acc += roif[roi * 128 + tid] * fcw[2048 + tid];
    red[tid] = acc;
    __syncthreads();
    for (int off = 128; off > 0; off >>= 1) {
        if (tid < off) red[tid] += red[tid + off];
        __syncthreads();
    }
    if (tid == 0)
        g_rroi[roi] = fmaxf((red[0] + fcb[0]) / DIV_COEF_C + RADIUS_C, MIN_R_C);
}

extern "C" void kernel_launch(void* const* d_in, const int* in_sizes, int n_in,
                              void* d_out, int out_size, void* d_ws, size_t ws_size,
                              hipStream_t stream) {
    const float* xyz   = (const float*)d_in[0];
    const float* feats = (const float*)d_in[1];
    const float* rois  = (const float*)d_in[2];
    const float* roif  = (const float*)d_in[3];
    const float* td    = (const float*)d_in[4];
    const float* pw0 = (const float*)d_in[5];
    const float* pg0 = (const float*)d_in[6];
    const float* pb0 = (const float*)d_in[7];
    const float* pw1 = (const float*)d_in[8];
    const float* pg1 = (const float*)d_in[9];
    const float* pb1 = (const float*)d_in[10];
    const float* fw0 = (const float*)d_in[11];
    const float* fg0 = (const float*)d_in[12];
    const float* fb0 = (const float*)d_in[13];
    const float* fw1 = (const float*)d_in[14];
    const float* fg1 = (const float*)d_in[15];
    const float* fb1 = (const float*)d_in[16];
    const float* fcw = (const float*)d_in[17];
    const float* fcb = (const float*)d_in[18];
    float* out = (float*)d_out;

    void* xa; hipGetSymbolAddress(&xa, HIP_SYMBOL(g_xa));
    void* xb; hipGetSymbolAddress(&xb, HIP_SYMBOL(g_xb));

    setup_kernel<<<(SETUP_N + 255) / 256, 256, 0, stream>>>(rois, fw1, out);
    grid_count_kernel<<<64, 256, 0, stream>>>(xyz);
    grid_prefix_kernel<<<2, 1024, 0, stream>>>();
    grid_scatter_kernel<<<64, 256, 0, stream>>>(xyz);

    // pred branch (16 samples, 32 ch, all fp32)
    bq_grid_kernel<SP><<<MTOT / 4, 256, 0, stream>>>(xyz, rois);
    mlp_passA_kernel<SP, CP, false><<<1024, 256, 0, stream>>>(xyz, feats, rois, pw0, xa);
    finalize_kernel<<<CP, 256, 0, stream>>>(pg0, pb0, (float)(MTOT * SP), 0, 1024);
    mlp_passB_kernel<SP, CP><<<1024, 128, 0, stream>>>(pw1, (const float*)xa, (float*)xb, 0);
    finalize_kernel<<<CP, 256, 0, stream>>>(pg1, pb1, (float)(MTOT * SP), 1, 1024);
    passC_roi_kernel<<<NROI, 256, 0, stream>>>(fcw, fcb, roif, (const float*)xb);

    // deform branch (32 samples, 64 ch, fp16 intermediates)
    bq_grid_kernel<SD><<<MTOT / 4, 256, 0, stream>>>(xyz, rois);
    mlp_passA_kernel<SD, CF, true><<<2048, 256, 0, stream>>>(xyz, feats, rois, fw0, xa);
    finalize_kernel<<<CF, 256, 0, stream>>>(fg0, fb0, (float)(MTOT * SD), 2, 2048);
    mlp_fB_kernel<<<2048, 256, 0, stream>>>((const __half*)xa, (__half*)xb);
    finalize_kernel<<<CF, 256, 0, stream>>>(fg1, fb1, (float)(MTOT * SD), 3, 2048);
    passC_f_kernel<<<MTOT / 2, 128, 0, stream>>>(xyz, rois, td, (const __half*)xb, out);
}